// Round 12
// baseline (66.570 us; speedup 1.0000x reference)
//
#include <hip/hip_runtime.h>
#include <math.h>

// MultiInterestExtractor — round 12: r9 with INTERLEAVED row->wave mapping.
// r11 post-mortem: rn[8] staging spilled at the (256,5) 102-VGPR cap; revert
// to rn[4]. r9 re-audit: BLOCKED mapping made wave 0 the critical path with
// min(slen,50) rows (mean 44) while waves 1-3 idled — block wall time is the
// MAX wave, not the mean. Interleaved (l = 4*rloc + w) balances all waves at
// ceil(slen/4) rows (mean 25): stage+PV groups for the slowest wave 11 -> 6.5.
// Keeps: 5 blocks/CU, slen-proportional staging (jmax groups), bf16-h LDS
// (XOR-swizzled uint2 slots), fixed-shift softmax (e = exp(s-B_k), hard
// bound, tanh in [-1,1]), plain-sum merge in the wave's dead h region.

#define LL 200
#define DD 64
#define AA 5
#define KK 4
#define WU2 832            // uint2 slots per wave region (52 rows x 16)
#define FREG (WU2 * 2)     // floats per region as merge scratch

__device__ __forceinline__ unsigned bf16_rne(float f) {   // finite inputs
    unsigned u = __float_as_uint(f);
    return (u + 0x7FFFu + ((u >> 16) & 1u)) >> 16;
}
__device__ __forceinline__ unsigned pk2(float lo, float hi) {
    return bf16_rne(lo) | (bf16_rne(hi) << 16);
}
__device__ __forceinline__ float lo16(unsigned u) { return __uint_as_float(u << 16); }
__device__ __forceinline__ float hi16(unsigned u) { return __uint_as_float(u & 0xFFFF0000u); }

__device__ __forceinline__ float fast_tanh(float x) {
    float e = __expf(2.f * x);                          // +inf for large x ok
    return 1.f - 2.f * __builtin_amdgcn_rcpf(e + 1.f);  // saturates to +/-1
}

__global__ __launch_bounds__(256, 5)
void mie_fused(const float* __restrict__ h_g,    // [N, L, D]
               const int*   __restrict__ slen_g, // [N]
               const float* __restrict__ W1w,    // [A, D]
               const float* __restrict__ W1b,    // [A]
               const float* __restrict__ W2w,    // [K, A]
               const float* __restrict__ W2b,    // [K]
               float*       __restrict__ out)    // [N, K, D]
{
    __shared__ uint2  hbuf[4 * WU2];        // 26624 B (bf16 h, 4 wave regions)
    __shared__ float4 p4s[4][52];           //  3328 B per-row e[k]
    __shared__ float  den_s[4][4][KK];      //   256 B [wave][rq][k]

    const int n    = blockIdx.x;
    const int t    = threadIdx.x;
    const int w    = t >> 6;                // wave id = row phase
    const int lane = t & 63;
    const int slen = slen_g[n];

    // interleaved assignment: wave w owns global rows l = 4*rloc + w < slen
    const int nrows = (slen > w) ? ((slen - w + 3) >> 2) : 0;   // 0..50
    uint2* hbw     = &hbuf[w * WU2];
    float* fregion = (float*)hbw;           // merge scratch (h dead by then)

    if (nrows == 0) {                       // only when slen < 4
        float4 z = {0.f, 0.f, 0.f, 0.f};
        #pragma unroll
        for (int q = 0; q < 4; ++q)
            *(float4*)&fregion[q * 256 + lane * 4] = z;
        if (lane < 4) *(float4*)&den_s[w][lane][0] = z;
    } else {
        const int nf4 = slen * 16;
        const float4* hn4 = (const float4*)(h_g + (size_t)n * (LL * DD));
        const int jmax = (nrows + 3) >> 2;          // 1..13 stage/PV groups

        // per-lane address offset: local row r = 4j + (lane>>4), col c = lane&15
        // global f4 = (4r + w)*16 + c = 256j + 64*(lane>>4) + 16w + c
        const int laneoff = 64 * (lane >> 4) + (lane & 15) + 16 * w;

        // ---- stage: rn[4]-chunked (cap-safe), jmax ∝ slen groups;
        //      4x256B segments per load instr; pack bf16, XOR swizzle ----
        for (int j0 = 0; j0 < jmax; j0 += 4) {
            float4 rn[4];
            #pragma unroll
            for (int u = 0; u < 4; ++u) {
                int j = j0 + u;
                if (j < jmax)
                    rn[u] = hn4[min(256 * j + laneoff, nf4 - 1)];  // clamp dup
            }
            #pragma unroll
            for (int u = 0; u < 4; ++u) {
                int j = j0 + u;
                if (j < jmax) {
                    int r = 4 * j + (lane >> 4), c = lane & 15;    // r <= 51
                    hbw[r * 16 + (c ^ (r & 15))] =
                        make_uint2(pk2(rn[u].x, rn[u].y), pk2(rn[u].z, rn[u].w));
                }
            }
        }

        // hard per-head score bound (tanh in [-1,1]): same shift everywhere
        float Bk[KK];
        #pragma unroll
        for (int k = 0; k < KK; ++k) {
            float b = fabsf(W2b[k]);
            #pragma unroll
            for (int a = 0; a < AA; ++a) b += fabsf(W2w[k * AA + a]);
            Bk[k] = b;
        }

        asm volatile("s_waitcnt lgkmcnt(0)" ::: "memory");

        // ---- scores: lane = local row (dup-clamped -> broadcast, free);
        //      W1 lane-uniform -> scalar loads ----
        const float4* W14 = (const float4*)W1w;
        const int rl = min(lane, nrows - 1);
        float a0 = W1b[0], a1 = W1b[1], a2 = W1b[2], a3 = W1b[3], a4 = W1b[4];
        #pragma unroll
        for (int i = 0; i < 16; ++i) {
            uint2 q = hbw[rl * 16 + (i ^ (rl & 15))];
            float hx = lo16(q.x), hy = hi16(q.x), hz = lo16(q.y), hw = hi16(q.y);
            float4 w0 = W14[0*16+i], w1 = W14[1*16+i], w2 = W14[2*16+i],
                   w3 = W14[3*16+i], w4 = W14[4*16+i];
            a0 = fmaf(hx, w0.x, fmaf(hy, w0.y, fmaf(hz, w0.z, fmaf(hw, w0.w, a0))));
            a1 = fmaf(hx, w1.x, fmaf(hy, w1.y, fmaf(hz, w1.z, fmaf(hw, w1.w, a1))));
            a2 = fmaf(hx, w2.x, fmaf(hy, w2.y, fmaf(hz, w2.z, fmaf(hw, w2.w, a2))));
            a3 = fmaf(hx, w3.x, fmaf(hy, w3.y, fmaf(hz, w3.z, fmaf(hw, w3.w, a3))));
            a4 = fmaf(hx, w4.x, fmaf(hy, w4.y, fmaf(hz, w4.z, fmaf(hw, w4.w, a4))));
        }
        const bool vrow = lane < nrows;
        const float t0 = fast_tanh(a0), t1 = fast_tanh(a1), t2 = fast_tanh(a2),
                    t3 = fast_tanh(a3), t4 = fast_tanh(a4);
        float e[KK];
        #pragma unroll
        for (int k = 0; k < KK; ++k) {
            float s = W2b[k];
            s = fmaf(t0, W2w[k*AA+0], s);
            s = fmaf(t1, W2w[k*AA+1], s);
            s = fmaf(t2, W2w[k*AA+2], s);
            s = fmaf(t3, W2w[k*AA+3], s);
            s = fmaf(t4, W2w[k*AA+4], s);
            e[k] = vrow ? __expf(s - Bk[k]) : 0.f;         // e in (0,1]
        }
        if (lane < 52)
            p4s[w][lane] = make_float4(e[0], e[1], e[2], e[3]); // pads: e=0

        asm volatile("s_waitcnt lgkmcnt(0)" ::: "memory");

        // ---- PV: lane = (rq = lane>>4 row-in-group, dc = lane&15 slot) ----
        const int rq = lane >> 4, dc = lane & 15;
        float4 acc0 = {0,0,0,0}, acc1 = {0,0,0,0}, acc2 = {0,0,0,0}, acc3 = {0,0,0,0};
        float dn0 = 0.f, dn1 = 0.f, dn2 = 0.f, dn3 = 0.f;
        for (int g = 0; g < jmax; ++g) {
            const int row = g * 4 + rq;                    // <= 51; pads e=0
            uint2 q = hbw[row * 16 + (dc ^ (row & 15))];
            float hx = lo16(q.x), hy = hi16(q.x), hz = lo16(q.y), hw = hi16(q.y);
            float4 pv = p4s[w][row];
            acc0.x = fmaf(pv.x, hx, acc0.x); acc0.y = fmaf(pv.x, hy, acc0.y);
            acc0.z = fmaf(pv.x, hz, acc0.z); acc0.w = fmaf(pv.x, hw, acc0.w);
            acc1.x = fmaf(pv.y, hx, acc1.x); acc1.y = fmaf(pv.y, hy, acc1.y);
            acc1.z = fmaf(pv.y, hz, acc1.z); acc1.w = fmaf(pv.y, hw, acc1.w);
            acc2.x = fmaf(pv.z, hx, acc2.x); acc2.y = fmaf(pv.z, hy, acc2.y);
            acc2.z = fmaf(pv.z, hz, acc2.z); acc2.w = fmaf(pv.z, hw, acc2.w);
            acc3.x = fmaf(pv.w, hx, acc3.x); acc3.y = fmaf(pv.w, hy, acc3.y);
            acc3.z = fmaf(pv.w, hz, acc3.z); acc3.w = fmaf(pv.w, hw, acc3.w);
            dn0 += pv.x; dn1 += pv.y; dn2 += pv.z; dn3 += pv.w;
        }

        // ---- merge: rq-partials into OWN dead h region (no shuffles) ----
        *(float4*)&fregion[rq * 256 + 0 * 64 + dc * 4] = acc0;
        *(float4*)&fregion[rq * 256 + 1 * 64 + dc * 4] = acc1;
        *(float4*)&fregion[rq * 256 + 2 * 64 + dc * 4] = acc2;
        *(float4*)&fregion[rq * 256 + 3 * 64 + dc * 4] = acc3;
        if (dc == 0)
            *(float4*)&den_s[w][rq][0] = make_float4(dn0, dn1, dn2, dn3);
    }

    __syncthreads();

    // ---- epilogue: sum 16 partials (4 waves x 4 rq) per output element ----
    {
        const float* fb = (const float*)hbuf;
        float s = 0.f;
        #pragma unroll
        for (int i = 0; i < 16; ++i)
            s += fb[(i >> 2) * FREG + (i & 3) * 256 + t];  // stride-1 in t
        const int k = t >> 6;
        float den = 0.f;
        #pragma unroll
        for (int i = 0; i < 16; ++i)
            den += den_s[i >> 2][i & 3][k];                // broadcast reads
        out[(size_t)n * (KK * DD) + t] = s / den;          // den>0 (slen>=1)
    }
}

extern "C" void kernel_launch(void* const* d_in, const int* in_sizes, int n_in,
                              void* d_out, int out_size, void* d_ws, size_t ws_size,
                              hipStream_t stream) {
    const float* h_g  = (const float*)d_in[0];
    const int*   slen = (const int*)  d_in[1];
    const float* W1w  = (const float*)d_in[2];
    const float* W1b  = (const float*)d_in[3];
    const float* W2w  = (const float*)d_in[4];
    const float* W2b  = (const float*)d_in[5];
    float*       outp = (float*)d_out;

    const int N = in_sizes[1];

    mie_fused<<<dim3(N), dim3(256), 0, stream>>>(h_g, slen, W1w, W1b, W2w, W2b, outp);
}

// Round 13
// 55.705 us; speedup vs baseline: 1.1950x; 1.1950x over previous
//
#include <hip/hip_runtime.h>
#include <math.h>

// MultiInterestExtractor — round 13: r9 (58.8us, best) + packed-fp32 math.
// r12 post-mortem: blocked > interleaved at 5 blocks/CU because the binding
// resource is AGGREGATE issue bandwidth (score pass is fixed-cost per active
// wave; blocked idles trailing waves -> fewer issued instrs). r9 structure
// restored verbatim; only change: score/PV inner loops use v_pk_fma_f32 via
// <2 x float> __builtin_elementwise_fma (exact fp32 pairs, bit-compatible),
// halving ~320 score FMAs and 16 PV FMAs per group. den adds packed too.

#define LL 200
#define DD 64
#define AA 5
#define KK 4
#define RPW 50             // rows per wave (blocked)
#define WU2 832            // uint2 slots per wave region (52 rows x 16)
#define FREG (WU2 * 2)     // floats per region as merge scratch

typedef float v2f __attribute__((ext_vector_type(2)));

__device__ __forceinline__ v2f fma2(v2f a, v2f b, v2f c) {
    return __builtin_elementwise_fma(a, b, c);   // -> v_pk_fma_f32
}

__device__ __forceinline__ unsigned bf16_rne(float f) {   // finite inputs
    unsigned u = __float_as_uint(f);
    return (u + 0x7FFFu + ((u >> 16) & 1u)) >> 16;
}
__device__ __forceinline__ unsigned pk2(float lo, float hi) {
    return bf16_rne(lo) | (bf16_rne(hi) << 16);
}
__device__ __forceinline__ float lo16(unsigned u) { return __uint_as_float(u << 16); }
__device__ __forceinline__ float hi16(unsigned u) { return __uint_as_float(u & 0xFFFF0000u); }

__device__ __forceinline__ float fast_tanh(float x) {
    float e = __expf(2.f * x);                          // +inf for large x ok
    return 1.f - 2.f * __builtin_amdgcn_rcpf(e + 1.f);  // saturates to +/-1
}

__global__ __launch_bounds__(256, 5)
void mie_fused(const float* __restrict__ h_g,    // [N, L, D]
               const int*   __restrict__ slen_g, // [N]
               const float* __restrict__ W1w,    // [A, D]
               const float* __restrict__ W1b,    // [A]
               const float* __restrict__ W2w,    // [K, A]
               const float* __restrict__ W2b,    // [K]
               float*       __restrict__ out)    // [N, K, D]
{
    __shared__ uint2  hbuf[4 * WU2];        // 26624 B (bf16 h, 4 wave regions)
    __shared__ float4 p4s[4][52];           //  3328 B per-row e[k]
    __shared__ float  den_s[4][4][KK];      //   256 B [wave][rq][k]

    const int n    = blockIdx.x;
    const int t    = threadIdx.x;
    const int w    = t >> 6;                // wave id
    const int lane = t & 63;
    const int slen = slen_g[n];

    // blocked assignment: wave w owns global rows [RPW*w, RPW*w + nrows)
    const int nrows = min(max(slen - w * RPW, 0), RPW);   // 0..50
    uint2* hbw     = &hbuf[w * WU2];
    float* fregion = (float*)hbw;           // merge scratch (h dead by then)

    if (nrows == 0) {
        // idle wave (mean 1.5 of 4): zero merge region + den, wait at barrier
        float4 z = {0.f, 0.f, 0.f, 0.f};
        #pragma unroll
        for (int q = 0; q < 4; ++q)
            *(float4*)&fregion[q * 256 + lane * 4] = z;
        if (lane < 4) *(float4*)&den_s[w][lane][0] = z;
    } else {
        const int nf4  = slen * 16;
        const float4* hn4 = (const float4*)(h_g + (size_t)n * (LL * DD));
        const int base = w * RPW * 16;              // first f4 of wave's span
        const int jmax = (nrows + 3) >> 2;          // 1..13 stage/PV groups

        // ---- stage: groups of 4 slots-of-64 (prefetch depth 4, 16 VGPR);
        //      each instr reads a contiguous 1KB; pack bf16, XOR swizzle ----
        for (int j0 = 0; j0 < jmax; j0 += 4) {
            float4 rn[4];
            #pragma unroll
            for (int u = 0; u < 4; ++u) {
                int i = (j0 + u) * 64 + lane;
                rn[u] = hn4[min(base + i, nf4 - 1)];   // clamp: L2 dup, finite
            }
            #pragma unroll
            for (int u = 0; u < 4; ++u) {
                int j = j0 + u;
                if (j < jmax) {
                    int i = j * 64 + lane;
                    int r = i >> 4, c = i & 15;        // r <= 51
                    hbw[r * 16 + (c ^ (r & 15))] =
                        make_uint2(pk2(rn[u].x, rn[u].y), pk2(rn[u].z, rn[u].w));
                }
            }
        }

        // hard per-head score bound (tanh in [-1,1]): same shift everywhere
        float Bk[KK];
        #pragma unroll
        for (int k = 0; k < KK; ++k) {
            float b = fabsf(W2b[k]);
            #pragma unroll
            for (int a = 0; a < AA; ++a) b += fabsf(W2w[k * AA + a]);
            Bk[k] = b;
        }

        asm volatile("s_waitcnt lgkmcnt(0)" ::: "memory");

        // ---- scores: lane = local row (dup-clamped to valid -> finite,
        //      broadcast reads free); W1 lane-uniform -> scalar loads.
        //      v2f accumulators -> v_pk_fma_f32 (2 FLOP-pairs/instr). ----
        const float4* W14 = (const float4*)W1w;
        const int rl = min(lane, nrows - 1);
        v2f A0 = {W1b[0], 0.f}, A1 = {W1b[1], 0.f}, A2 = {W1b[2], 0.f},
            A3 = {W1b[3], 0.f}, A4 = {W1b[4], 0.f};
        #pragma unroll
        for (int i = 0; i < 16; ++i) {
            uint2 q = hbw[rl * 16 + (i ^ (rl & 15))];
            v2f h01 = {lo16(q.x), hi16(q.x)};
            v2f h23 = {lo16(q.y), hi16(q.y)};
            float4 w0 = W14[0*16+i], w1 = W14[1*16+i], w2 = W14[2*16+i],
                   w3 = W14[3*16+i], w4 = W14[4*16+i];
            v2f w0a = {w0.x, w0.y}, w0b = {w0.z, w0.w};
            v2f w1a = {w1.x, w1.y}, w1b = {w1.z, w1.w};
            v2f w2a = {w2.x, w2.y}, w2b = {w2.z, w2.w};
            v2f w3a = {w3.x, w3.y}, w3b = {w3.z, w3.w};
            v2f w4a = {w4.x, w4.y}, w4b = {w4.z, w4.w};
            A0 = fma2(h01, w0a, A0); A0 = fma2(h23, w0b, A0);
            A1 = fma2(h01, w1a, A1); A1 = fma2(h23, w1b, A1);
            A2 = fma2(h01, w2a, A2); A2 = fma2(h23, w2b, A2);
            A3 = fma2(h01, w3a, A3); A3 = fma2(h23, w3b, A3);
            A4 = fma2(h01, w4a, A4); A4 = fma2(h23, w4b, A4);
        }
        const float a0 = A0.x + A0.y, a1 = A1.x + A1.y, a2 = A2.x + A2.y,
                    a3 = A3.x + A3.y, a4 = A4.x + A4.y;
        const bool vrow = lane < nrows;
        const float t0 = fast_tanh(a0), t1 = fast_tanh(a1), t2 = fast_tanh(a2),
                    t3 = fast_tanh(a3), t4 = fast_tanh(a4);
        float e[KK];
        #pragma unroll
        for (int k = 0; k < KK; ++k) {
            float s = W2b[k];
            s = fmaf(t0, W2w[k*AA+0], s);
            s = fmaf(t1, W2w[k*AA+1], s);
            s = fmaf(t2, W2w[k*AA+2], s);
            s = fmaf(t3, W2w[k*AA+3], s);
            s = fmaf(t4, W2w[k*AA+4], s);
            e[k] = vrow ? __expf(s - Bk[k]) : 0.f;         // e in (0,1]
        }
        if (lane < 52)
            p4s[w][lane] = make_float4(e[0], e[1], e[2], e[3]); // pads: e=0

        asm volatile("s_waitcnt lgkmcnt(0)" ::: "memory");

        // ---- PV: lane = (rq = lane>>4 row-in-group, dc = lane&15 slot);
        //      v2f accumulators -> v_pk_fma_f32. ----
        const int rq = lane >> 4, dc = lane & 15;
        v2f c0a = {0,0}, c0b = {0,0}, c1a = {0,0}, c1b = {0,0},
            c2a = {0,0}, c2b = {0,0}, c3a = {0,0}, c3b = {0,0};
        v2f dn01 = {0,0}, dn23 = {0,0};
        for (int g = 0; g < jmax; ++g) {
            const int row = g * 4 + rq;                    // <= 51; pads e=0
            uint2 q = hbw[row * 16 + (dc ^ (row & 15))];
            v2f h01 = {lo16(q.x), hi16(q.x)};
            v2f h23 = {lo16(q.y), hi16(q.y)};
            float4 pv = p4s[w][row];
            v2f p0 = {pv.x, pv.x}, p1 = {pv.y, pv.y},
                p2 = {pv.z, pv.z}, p3 = {pv.w, pv.w};
            c0a = fma2(p0, h01, c0a); c0b = fma2(p0, h23, c0b);
            c1a = fma2(p1, h01, c1a); c1b = fma2(p1, h23, c1b);
            c2a = fma2(p2, h01, c2a); c2b = fma2(p2, h23, c2b);
            c3a = fma2(p3, h01, c3a); c3b = fma2(p3, h23, c3b);
            v2f pv01 = {pv.x, pv.y}, pv23 = {pv.z, pv.w};
            dn01 += pv01; dn23 += pv23;                    // v_pk_add_f32
        }

        // ---- merge: rq-partials into OWN dead h region (no shuffles) ----
        *(float4*)&fregion[rq * 256 + 0 * 64 + dc * 4] =
            make_float4(c0a.x, c0a.y, c0b.x, c0b.y);
        *(float4*)&fregion[rq * 256 + 1 * 64 + dc * 4] =
            make_float4(c1a.x, c1a.y, c1b.x, c1b.y);
        *(float4*)&fregion[rq * 256 + 2 * 64 + dc * 4] =
            make_float4(c2a.x, c2a.y, c2b.x, c2b.y);
        *(float4*)&fregion[rq * 256 + 3 * 64 + dc * 4] =
            make_float4(c3a.x, c3a.y, c3b.x, c3b.y);
        if (dc == 0)
            *(float4*)&den_s[w][rq][0] =
                make_float4(dn01.x, dn01.y, dn23.x, dn23.y);
    }

    __syncthreads();

    // ---- epilogue: sum 16 partials (4 waves x 4 rq) per output element ----
    {
        const float* fb = (const float*)hbuf;
        float s = 0.f;
        #pragma unroll
        for (int i = 0; i < 16; ++i)
            s += fb[(i >> 2) * FREG + (i & 3) * 256 + t];  // stride-1 in t
        const int k = t >> 6;
        float den = 0.f;
        #pragma unroll
        for (int i = 0; i < 16; ++i)
            den += den_s[i >> 2][i & 3][k];                // broadcast reads
        out[(size_t)n * (KK * DD) + t] = s / den;          // den>0 (slen>=1)
    }
}

extern "C" void kernel_launch(void* const* d_in, const int* in_sizes, int n_in,
                              void* d_out, int out_size, void* d_ws, size_t ws_size,
                              hipStream_t stream) {
    const float* h_g  = (const float*)d_in[0];
    const int*   slen = (const int*)  d_in[1];
    const float* W1w  = (const float*)d_in[2];
    const float* W1b  = (const float*)d_in[3];
    const float* W2w  = (const float*)d_in[4];
    const float* W2b  = (const float*)d_in[5];
    float*       outp = (float*)d_out;

    const int N = in_sizes[1];

    mie_fused<<<dim3(N), dim3(256), 0, stream>>>(h_g, slen, W1w, W1b, W2w, W2b, outp);
}

// Round 14
// 53.253 us; speedup vs baseline: 1.2501x; 1.0460x over previous
//
#include <hip/hip_runtime.h>
#include <math.h>

// MultiInterestExtractor — round 14: r13 (55.7us, best) + v_cvt_pk_bf16_f32.
// r13 post-mortem: pk_fma confirmed the aggregate-issue model (-3.1us).
// Largest remaining VALU item: hand-rolled RNE bf16 pack in staging
// (~20 ops/float4, ~500 instr/block). gfx950's v_cvt_pk_bf16_f32 does a
// 2xf32 -> packed-2xbf16 RNE convert in ONE instruction (same rounding ->
// bit-identical output). Staging pack: 20 -> 2 ops per float4.
// Everything else identical to r13: blocked row->wave (idle waves free
// issue slots), 5 blocks/CU, bf16-h LDS XOR-swizzled, fixed-shift softmax,
// pk_fma score/PV, plain-sum merge in the wave's dead h region.

#define LL 200
#define DD 64
#define AA 5
#define KK 4
#define RPW 50             // rows per wave (blocked)
#define WU2 832            // uint2 slots per wave region (52 rows x 16)
#define FREG (WU2 * 2)     // floats per region as merge scratch

typedef float v2f __attribute__((ext_vector_type(2)));

__device__ __forceinline__ v2f fma2(v2f a, v2f b, v2f c) {
    return __builtin_elementwise_fma(a, b, c);   // -> v_pk_fma_f32
}

__device__ __forceinline__ unsigned pk2(float lo, float hi) {
    unsigned r;                                   // RNE, finite inputs
    asm("v_cvt_pk_bf16_f32 %0, %1, %2" : "=v"(r) : "v"(lo), "v"(hi));
    return r;
}
__device__ __forceinline__ float lo16(unsigned u) { return __uint_as_float(u << 16); }
__device__ __forceinline__ float hi16(unsigned u) { return __uint_as_float(u & 0xFFFF0000u); }

__device__ __forceinline__ float fast_tanh(float x) {
    float e = __expf(2.f * x);                          // +inf for large x ok
    return 1.f - 2.f * __builtin_amdgcn_rcpf(e + 1.f);  // saturates to +/-1
}

__global__ __launch_bounds__(256, 5)
void mie_fused(const float* __restrict__ h_g,    // [N, L, D]
               const int*   __restrict__ slen_g, // [N]
               const float* __restrict__ W1w,    // [A, D]
               const float* __restrict__ W1b,    // [A]
               const float* __restrict__ W2w,    // [K, A]
               const float* __restrict__ W2b,    // [K]
               float*       __restrict__ out)    // [N, K, D]
{
    __shared__ uint2  hbuf[4 * WU2];        // 26624 B (bf16 h, 4 wave regions)
    __shared__ float4 p4s[4][52];           //  3328 B per-row e[k]
    __shared__ float  den_s[4][4][KK];      //   256 B [wave][rq][k]

    const int n    = blockIdx.x;
    const int t    = threadIdx.x;
    const int w    = t >> 6;                // wave id
    const int lane = t & 63;
    const int slen = slen_g[n];

    // blocked assignment: wave w owns global rows [RPW*w, RPW*w + nrows)
    const int nrows = min(max(slen - w * RPW, 0), RPW);   // 0..50
    uint2* hbw     = &hbuf[w * WU2];
    float* fregion = (float*)hbw;           // merge scratch (h dead by then)

    if (nrows == 0) {
        // idle wave (mean 1.5 of 4): zero merge region + den, wait at barrier
        float4 z = {0.f, 0.f, 0.f, 0.f};
        #pragma unroll
        for (int q = 0; q < 4; ++q)
            *(float4*)&fregion[q * 256 + lane * 4] = z;
        if (lane < 4) *(float4*)&den_s[w][lane][0] = z;
    } else {
        const int nf4  = slen * 16;
        const float4* hn4 = (const float4*)(h_g + (size_t)n * (LL * DD));
        const int base = w * RPW * 16;              // first f4 of wave's span
        const int jmax = (nrows + 3) >> 2;          // 1..13 stage/PV groups

        // ---- stage: groups of 4 slots-of-64 (prefetch depth 4, 16 VGPR);
        //      each instr reads a contiguous 1KB; cvt_pk bf16, XOR swizzle ----
        for (int j0 = 0; j0 < jmax; j0 += 4) {
            float4 rn[4];
            #pragma unroll
            for (int u = 0; u < 4; ++u) {
                int i = (j0 + u) * 64 + lane;
                rn[u] = hn4[min(base + i, nf4 - 1)];   // clamp: L2 dup, finite
            }
            #pragma unroll
            for (int u = 0; u < 4; ++u) {
                int j = j0 + u;
                if (j < jmax) {
                    int i = j * 64 + lane;
                    int r = i >> 4, c = i & 15;        // r <= 51
                    hbw[r * 16 + (c ^ (r & 15))] =
                        make_uint2(pk2(rn[u].x, rn[u].y), pk2(rn[u].z, rn[u].w));
                }
            }
        }

        // hard per-head score bound (tanh in [-1,1]): same shift everywhere
        float Bk[KK];
        #pragma unroll
        for (int k = 0; k < KK; ++k) {
            float b = fabsf(W2b[k]);
            #pragma unroll
            for (int a = 0; a < AA; ++a) b += fabsf(W2w[k * AA + a]);
            Bk[k] = b;
        }

        asm volatile("s_waitcnt lgkmcnt(0)" ::: "memory");

        // ---- scores: lane = local row (dup-clamped to valid -> finite,
        //      broadcast reads free); W1 lane-uniform -> scalar loads.
        //      v2f accumulators -> v_pk_fma_f32 (2 FLOP-pairs/instr). ----
        const float4* W14 = (const float4*)W1w;
        const int rl = min(lane, nrows - 1);
        v2f A0 = {W1b[0], 0.f}, A1 = {W1b[1], 0.f}, A2 = {W1b[2], 0.f},
            A3 = {W1b[3], 0.f}, A4 = {W1b[4], 0.f};
        #pragma unroll
        for (int i = 0; i < 16; ++i) {
            uint2 q = hbw[rl * 16 + (i ^ (rl & 15))];
            v2f h01 = {lo16(q.x), hi16(q.x)};
            v2f h23 = {lo16(q.y), hi16(q.y)};
            float4 w0 = W14[0*16+i], w1 = W14[1*16+i], w2 = W14[2*16+i],
                   w3 = W14[3*16+i], w4 = W14[4*16+i];
            v2f w0a = {w0.x, w0.y}, w0b = {w0.z, w0.w};
            v2f w1a = {w1.x, w1.y}, w1b = {w1.z, w1.w};
            v2f w2a = {w2.x, w2.y}, w2b = {w2.z, w2.w};
            v2f w3a = {w3.x, w3.y}, w3b = {w3.z, w3.w};
            v2f w4a = {w4.x, w4.y}, w4b = {w4.z, w4.w};
            A0 = fma2(h01, w0a, A0); A0 = fma2(h23, w0b, A0);
            A1 = fma2(h01, w1a, A1); A1 = fma2(h23, w1b, A1);
            A2 = fma2(h01, w2a, A2); A2 = fma2(h23, w2b, A2);
            A3 = fma2(h01, w3a, A3); A3 = fma2(h23, w3b, A3);
            A4 = fma2(h01, w4a, A4); A4 = fma2(h23, w4b, A4);
        }
        const float a0 = A0.x + A0.y, a1 = A1.x + A1.y, a2 = A2.x + A2.y,
                    a3 = A3.x + A3.y, a4 = A4.x + A4.y;
        const bool vrow = lane < nrows;
        const float t0 = fast_tanh(a0), t1 = fast_tanh(a1), t2 = fast_tanh(a2),
                    t3 = fast_tanh(a3), t4 = fast_tanh(a4);
        float e[KK];
        #pragma unroll
        for (int k = 0; k < KK; ++k) {
            float s = W2b[k];
            s = fmaf(t0, W2w[k*AA+0], s);
            s = fmaf(t1, W2w[k*AA+1], s);
            s = fmaf(t2, W2w[k*AA+2], s);
            s = fmaf(t3, W2w[k*AA+3], s);
            s = fmaf(t4, W2w[k*AA+4], s);
            e[k] = vrow ? __expf(s - Bk[k]) : 0.f;         // e in (0,1]
        }
        if (lane < 52)
            p4s[w][lane] = make_float4(e[0], e[1], e[2], e[3]); // pads: e=0

        asm volatile("s_waitcnt lgkmcnt(0)" ::: "memory");

        // ---- PV: lane = (rq = lane>>4 row-in-group, dc = lane&15 slot);
        //      v2f accumulators -> v_pk_fma_f32. ----
        const int rq = lane >> 4, dc = lane & 15;
        v2f c0a = {0,0}, c0b = {0,0}, c1a = {0,0}, c1b = {0,0},
            c2a = {0,0}, c2b = {0,0}, c3a = {0,0}, c3b = {0,0};
        v2f dn01 = {0,0}, dn23 = {0,0};
        for (int g = 0; g < jmax; ++g) {
            const int row = g * 4 + rq;                    // <= 51; pads e=0
            uint2 q = hbw[row * 16 + (dc ^ (row & 15))];
            v2f h01 = {lo16(q.x), hi16(q.x)};
            v2f h23 = {lo16(q.y), hi16(q.y)};
            float4 pv = p4s[w][row];
            v2f p0 = {pv.x, pv.x}, p1 = {pv.y, pv.y},
                p2 = {pv.z, pv.z}, p3 = {pv.w, pv.w};
            c0a = fma2(p0, h01, c0a); c0b = fma2(p0, h23, c0b);
            c1a = fma2(p1, h01, c1a); c1b = fma2(p1, h23, c1b);
            c2a = fma2(p2, h01, c2a); c2b = fma2(p2, h23, c2b);
            c3a = fma2(p3, h01, c3a); c3b = fma2(p3, h23, c3b);
            v2f pv01 = {pv.x, pv.y}, pv23 = {pv.z, pv.w};
            dn01 += pv01; dn23 += pv23;                    // v_pk_add_f32
        }

        // ---- merge: rq-partials into OWN dead h region (no shuffles) ----
        *(float4*)&fregion[rq * 256 + 0 * 64 + dc * 4] =
            make_float4(c0a.x, c0a.y, c0b.x, c0b.y);
        *(float4*)&fregion[rq * 256 + 1 * 64 + dc * 4] =
            make_float4(c1a.x, c1a.y, c1b.x, c1b.y);
        *(float4*)&fregion[rq * 256 + 2 * 64 + dc * 4] =
            make_float4(c2a.x, c2a.y, c2b.x, c2b.y);
        *(float4*)&fregion[rq * 256 + 3 * 64 + dc * 4] =
            make_float4(c3a.x, c3a.y, c3b.x, c3b.y);
        if (dc == 0)
            *(float4*)&den_s[w][rq][0] =
                make_float4(dn01.x, dn01.y, dn23.x, dn23.y);
    }

    __syncthreads();

    // ---- epilogue: sum 16 partials (4 waves x 4 rq) per output element ----
    {
        const float* fb = (const float*)hbuf;
        float s = 0.f;
        #pragma unroll
        for (int i = 0; i < 16; ++i)
            s += fb[(i >> 2) * FREG + (i & 3) * 256 + t];  // stride-1 in t
        const int k = t >> 6;
        float den = 0.f;
        #pragma unroll
        for (int i = 0; i < 16; ++i)
            den += den_s[i >> 2][i & 3][k];                // broadcast reads
        out[(size_t)n * (KK * DD) + t] = s / den;          // den>0 (slen>=1)
    }
}

extern "C" void kernel_launch(void* const* d_in, const int* in_sizes, int n_in,
                              void* d_out, int out_size, void* d_ws, size_t ws_size,
                              hipStream_t stream) {
    const float* h_g  = (const float*)d_in[0];
    const int*   slen = (const int*)  d_in[1];
    const float* W1w  = (const float*)d_in[2];
    const float* W1b  = (const float*)d_in[3];
    const float* W2w  = (const float*)d_in[4];
    const float* W2b  = (const float*)d_in[5];
    float*       outp = (float*)d_out;

    const int N = in_sizes[1];

    mie_fused<<<dim3(N), dim3(256), 0, stream>>>(h_g, slen, W1w, W1b, W2w, W2b, outp);
}

// Round 15
// 52.556 us; speedup vs baseline: 1.2666x; 1.0133x over previous
//
#include <hip/hip_runtime.h>
#include <math.h>

// MultiInterestExtractor — round 14: r13 (55.7us, best) + v_cvt_pk_bf16_f32.
// r13 post-mortem: pk_fma confirmed the aggregate-issue model (-3.1us).
// Largest remaining VALU item: hand-rolled RNE bf16 pack in staging
// (~20 ops/float4, ~500 instr/block). gfx950's v_cvt_pk_bf16_f32 does a
// 2xf32 -> packed-2xbf16 RNE convert in ONE instruction (same rounding ->
// bit-identical output). Staging pack: 20 -> 2 ops per float4.
// Everything else identical to r13: blocked row->wave (idle waves free
// issue slots), 5 blocks/CU, bf16-h LDS XOR-swizzled, fixed-shift softmax,
// pk_fma score/PV, plain-sum merge in the wave's dead h region.

#define LL 200
#define DD 64
#define AA 5
#define KK 4
#define RPW 50             // rows per wave (blocked)
#define WU2 832            // uint2 slots per wave region (52 rows x 16)
#define FREG (WU2 * 2)     // floats per region as merge scratch

typedef float v2f __attribute__((ext_vector_type(2)));

__device__ __forceinline__ v2f fma2(v2f a, v2f b, v2f c) {
    return __builtin_elementwise_fma(a, b, c);   // -> v_pk_fma_f32
}

__device__ __forceinline__ unsigned pk2(float lo, float hi) {
    unsigned r;                                   // RNE, finite inputs
    asm("v_cvt_pk_bf16_f32 %0, %1, %2" : "=v"(r) : "v"(lo), "v"(hi));
    return r;
}
__device__ __forceinline__ float lo16(unsigned u) { return __uint_as_float(u << 16); }
__device__ __forceinline__ float hi16(unsigned u) { return __uint_as_float(u & 0xFFFF0000u); }

__device__ __forceinline__ float fast_tanh(float x) {
    float e = __expf(2.f * x);                          // +inf for large x ok
    return 1.f - 2.f * __builtin_amdgcn_rcpf(e + 1.f);  // saturates to +/-1
}

__global__ __launch_bounds__(256, 5)
void mie_fused(const float* __restrict__ h_g,    // [N, L, D]
               const int*   __restrict__ slen_g, // [N]
               const float* __restrict__ W1w,    // [A, D]
               const float* __restrict__ W1b,    // [A]
               const float* __restrict__ W2w,    // [K, A]
               const float* __restrict__ W2b,    // [K]
               float*       __restrict__ out)    // [N, K, D]
{
    __shared__ uint2  hbuf[4 * WU2];        // 26624 B (bf16 h, 4 wave regions)
    __shared__ float4 p4s[4][52];           //  3328 B per-row e[k]
    __shared__ float  den_s[4][4][KK];      //   256 B [wave][rq][k]

    const int n    = blockIdx.x;
    const int t    = threadIdx.x;
    const int w    = t >> 6;                // wave id
    const int lane = t & 63;
    const int slen = slen_g[n];

    // blocked assignment: wave w owns global rows [RPW*w, RPW*w + nrows)
    const int nrows = min(max(slen - w * RPW, 0), RPW);   // 0..50
    uint2* hbw     = &hbuf[w * WU2];
    float* fregion = (float*)hbw;           // merge scratch (h dead by then)

    if (nrows == 0) {
        // idle wave (mean 1.5 of 4): zero merge region + den, wait at barrier
        float4 z = {0.f, 0.f, 0.f, 0.f};
        #pragma unroll
        for (int q = 0; q < 4; ++q)
            *(float4*)&fregion[q * 256 + lane * 4] = z;
        if (lane < 4) *(float4*)&den_s[w][lane][0] = z;
    } else {
        const int nf4  = slen * 16;
        const float4* hn4 = (const float4*)(h_g + (size_t)n * (LL * DD));
        const int base = w * RPW * 16;              // first f4 of wave's span
        const int jmax = (nrows + 3) >> 2;          // 1..13 stage/PV groups

        // ---- stage: groups of 4 slots-of-64 (prefetch depth 4, 16 VGPR);
        //      each instr reads a contiguous 1KB; cvt_pk bf16, XOR swizzle ----
        for (int j0 = 0; j0 < jmax; j0 += 4) {
            float4 rn[4];
            #pragma unroll
            for (int u = 0; u < 4; ++u) {
                int i = (j0 + u) * 64 + lane;
                rn[u] = hn4[min(base + i, nf4 - 1)];   // clamp: L2 dup, finite
            }
            #pragma unroll
            for (int u = 0; u < 4; ++u) {
                int j = j0 + u;
                if (j < jmax) {
                    int i = j * 64 + lane;
                    int r = i >> 4, c = i & 15;        // r <= 51
                    hbw[r * 16 + (c ^ (r & 15))] =
                        make_uint2(pk2(rn[u].x, rn[u].y), pk2(rn[u].z, rn[u].w));
                }
            }
        }

        // hard per-head score bound (tanh in [-1,1]): same shift everywhere
        float Bk[KK];
        #pragma unroll
        for (int k = 0; k < KK; ++k) {
            float b = fabsf(W2b[k]);
            #pragma unroll
            for (int a = 0; a < AA; ++a) b += fabsf(W2w[k * AA + a]);
            Bk[k] = b;
        }

        asm volatile("s_waitcnt lgkmcnt(0)" ::: "memory");

        // ---- scores: lane = local row (dup-clamped to valid -> finite,
        //      broadcast reads free); W1 lane-uniform -> scalar loads.
        //      v2f accumulators -> v_pk_fma_f32 (2 FLOP-pairs/instr). ----
        const float4* W14 = (const float4*)W1w;
        const int rl = min(lane, nrows - 1);
        v2f A0 = {W1b[0], 0.f}, A1 = {W1b[1], 0.f}, A2 = {W1b[2], 0.f},
            A3 = {W1b[3], 0.f}, A4 = {W1b[4], 0.f};
        #pragma unroll
        for (int i = 0; i < 16; ++i) {
            uint2 q = hbw[rl * 16 + (i ^ (rl & 15))];
            v2f h01 = {lo16(q.x), hi16(q.x)};
            v2f h23 = {lo16(q.y), hi16(q.y)};
            float4 w0 = W14[0*16+i], w1 = W14[1*16+i], w2 = W14[2*16+i],
                   w3 = W14[3*16+i], w4 = W14[4*16+i];
            v2f w0a = {w0.x, w0.y}, w0b = {w0.z, w0.w};
            v2f w1a = {w1.x, w1.y}, w1b = {w1.z, w1.w};
            v2f w2a = {w2.x, w2.y}, w2b = {w2.z, w2.w};
            v2f w3a = {w3.x, w3.y}, w3b = {w3.z, w3.w};
            v2f w4a = {w4.x, w4.y}, w4b = {w4.z, w4.w};
            A0 = fma2(h01, w0a, A0); A0 = fma2(h23, w0b, A0);
            A1 = fma2(h01, w1a, A1); A1 = fma2(h23, w1b, A1);
            A2 = fma2(h01, w2a, A2); A2 = fma2(h23, w2b, A2);
            A3 = fma2(h01, w3a, A3); A3 = fma2(h23, w3b, A3);
            A4 = fma2(h01, w4a, A4); A4 = fma2(h23, w4b, A4);
        }
        const float a0 = A0.x + A0.y, a1 = A1.x + A1.y, a2 = A2.x + A2.y,
                    a3 = A3.x + A3.y, a4 = A4.x + A4.y;
        const bool vrow = lane < nrows;
        const float t0 = fast_tanh(a0), t1 = fast_tanh(a1), t2 = fast_tanh(a2),
                    t3 = fast_tanh(a3), t4 = fast_tanh(a4);
        float e[KK];
        #pragma unroll
        for (int k = 0; k < KK; ++k) {
            float s = W2b[k];
            s = fmaf(t0, W2w[k*AA+0], s);
            s = fmaf(t1, W2w[k*AA+1], s);
            s = fmaf(t2, W2w[k*AA+2], s);
            s = fmaf(t3, W2w[k*AA+3], s);
            s = fmaf(t4, W2w[k*AA+4], s);
            e[k] = vrow ? __expf(s - Bk[k]) : 0.f;         // e in (0,1]
        }
        if (lane < 52)
            p4s[w][lane] = make_float4(e[0], e[1], e[2], e[3]); // pads: e=0

        asm volatile("s_waitcnt lgkmcnt(0)" ::: "memory");

        // ---- PV: lane = (rq = lane>>4 row-in-group, dc = lane&15 slot);
        //      v2f accumulators -> v_pk_fma_f32. ----
        const int rq = lane >> 4, dc = lane & 15;
        v2f c0a = {0,0}, c0b = {0,0}, c1a = {0,0}, c1b = {0,0},
            c2a = {0,0}, c2b = {0,0}, c3a = {0,0}, c3b = {0,0};
        v2f dn01 = {0,0}, dn23 = {0,0};
        for (int g = 0; g < jmax; ++g) {
            const int row = g * 4 + rq;                    // <= 51; pads e=0
            uint2 q = hbw[row * 16 + (dc ^ (row & 15))];
            v2f h01 = {lo16(q.x), hi16(q.x)};
            v2f h23 = {lo16(q.y), hi16(q.y)};
            float4 pv = p4s[w][row];
            v2f p0 = {pv.x, pv.x}, p1 = {pv.y, pv.y},
                p2 = {pv.z, pv.z}, p3 = {pv.w, pv.w};
            c0a = fma2(p0, h01, c0a); c0b = fma2(p0, h23, c0b);
            c1a = fma2(p1, h01, c1a); c1b = fma2(p1, h23, c1b);
            c2a = fma2(p2, h01, c2a); c2b = fma2(p2, h23, c2b);
            c3a = fma2(p3, h01, c3a); c3b = fma2(p3, h23, c3b);
            v2f pv01 = {pv.x, pv.y}, pv23 = {pv.z, pv.w};
            dn01 += pv01; dn23 += pv23;                    // v_pk_add_f32
        }

        // ---- merge: rq-partials into OWN dead h region (no shuffles) ----
        *(float4*)&fregion[rq * 256 + 0 * 64 + dc * 4] =
            make_float4(c0a.x, c0a.y, c0b.x, c0b.y);
        *(float4*)&fregion[rq * 256 + 1 * 64 + dc * 4] =
            make_float4(c1a.x, c1a.y, c1b.x, c1b.y);
        *(float4*)&fregion[rq * 256 + 2 * 64 + dc * 4] =
            make_float4(c2a.x, c2a.y, c2b.x, c2b.y);
        *(float4*)&fregion[rq * 256 + 3 * 64 + dc * 4] =
            make_float4(c3a.x, c3a.y, c3b.x, c3b.y);
        if (dc == 0)
            *(float4*)&den_s[w][rq][0] =
                make_float4(dn01.x, dn01.y, dn23.x, dn23.y);
    }

    __syncthreads();

    // ---- epilogue: sum 16 partials (4 waves x 4 rq) per output element ----
    {
        const float* fb = (const float*)hbuf;
        float s = 0.f;
        #pragma unroll
        for (int i = 0; i < 16; ++i)
            s += fb[(i >> 2) * FREG + (i & 3) * 256 + t];  // stride-1 in t
        const int k = t >> 6;
        float den = 0.f;
        #pragma unroll
        for (int i = 0; i < 16; ++i)
            den += den_s[i >> 2][i & 3][k];                // broadcast reads
        out[(size_t)n * (KK * DD) + t] = s / den;          // den>0 (slen>=1)
    }
}

extern "C" void kernel_launch(void* const* d_in, const int* in_sizes, int n_in,
                              void* d_out, int out_size, void* d_ws, size_t ws_size,
                              hipStream_t stream) {
    const float* h_g  = (const float*)d_in[0];
    const int*   slen = (const int*)  d_in[1];
    const float* W1w  = (const float*)d_in[2];
    const float* W1b  = (const float*)d_in[3];
    const float* W2w  = (const float*)d_in[4];
    const float* W2b  = (const float*)d_in[5];
    float*       outp = (float*)d_out;

    const int N = in_sizes[1];

    mie_fused<<<dim3(N), dim3(256), 0, stream>>>(h_g, slen, W1w, W1b, W2w, W2b, outp);
}

// Round 16
// 51.774 us; speedup vs baseline: 1.2858x; 1.0151x over previous
//
#include <hip/hip_runtime.h>
#include <math.h>

// MultiInterestExtractor — round 16: r15 (52.6us, best) + active-only merge.
// r15 post-mortem: cvt_pk matched prediction (-3.1us) — regime confirmed as
// HBM-latency/issue co-bound (~3us per ~500 instr/block removed).
// Next-largest fixed item: merge/epilogue touched all 16 partials and idle
// waves zeroed their region (17 LDS writes) just so the epilogue could read
// it back. Blocked mapping => active waves are exactly 0..nact-1,
// nact = ceil(slen/50), block-uniform. Now: idle waves skip straight to the
// barrier; epilogue sums only the nact active regions (uniform guards).
// ~-70 wave LDS ops/block. Numerics identical (inactive regions never read).
// Carried from r15: blocked row->wave, 5 blocks/CU, bf16-h LDS XOR-swizzled,
// v_cvt_pk_bf16_f32 staging, pk_fma score/PV, fixed-shift softmax
// (e = exp(s - B_k), hard bound, tanh in [-1,1]), dead-region merge.

#define LL 200
#define DD 64
#define AA 5
#define KK 4
#define RPW 50             // rows per wave (blocked)
#define WU2 832            // uint2 slots per wave region (52 rows x 16)
#define FREG (WU2 * 2)     // floats per region as merge scratch

typedef float v2f __attribute__((ext_vector_type(2)));

__device__ __forceinline__ v2f fma2(v2f a, v2f b, v2f c) {
    return __builtin_elementwise_fma(a, b, c);   // -> v_pk_fma_f32
}

__device__ __forceinline__ unsigned pk2(float lo, float hi) {
    unsigned r;                                   // RNE, finite inputs
    asm("v_cvt_pk_bf16_f32 %0, %1, %2" : "=v"(r) : "v"(lo), "v"(hi));
    return r;
}
__device__ __forceinline__ float lo16(unsigned u) { return __uint_as_float(u << 16); }
__device__ __forceinline__ float hi16(unsigned u) { return __uint_as_float(u & 0xFFFF0000u); }

__device__ __forceinline__ float fast_tanh(float x) {
    float e = __expf(2.f * x);                          // +inf for large x ok
    return 1.f - 2.f * __builtin_amdgcn_rcpf(e + 1.f);  // saturates to +/-1
}

__global__ __launch_bounds__(256, 5)
void mie_fused(const float* __restrict__ h_g,    // [N, L, D]
               const int*   __restrict__ slen_g, // [N]
               const float* __restrict__ W1w,    // [A, D]
               const float* __restrict__ W1b,    // [A]
               const float* __restrict__ W2w,    // [K, A]
               const float* __restrict__ W2b,    // [K]
               float*       __restrict__ out)    // [N, K, D]
{
    __shared__ uint2  hbuf[4 * WU2];        // 26624 B (bf16 h, 4 wave regions)
    __shared__ float4 p4s[4][52];           //  3328 B per-row e[k]
    __shared__ float  den_s[4][4][KK];      //   256 B [wave][rq][k]

    const int n    = blockIdx.x;
    const int t    = threadIdx.x;
    const int w    = t >> 6;                // wave id
    const int lane = t & 63;
    const int slen = slen_g[n];

    // blocked assignment: wave w owns global rows [RPW*w, RPW*w + nrows)
    const int nrows = min(max(slen - w * RPW, 0), RPW);   // 0..50
    const int nact  = (slen + RPW - 1) / RPW;             // active waves 1..4
    uint2* hbw     = &hbuf[w * WU2];
    float* fregion = (float*)hbw;           // merge scratch (h dead by then)

    if (nrows > 0) {                        // idle waves: straight to barrier
        const int nf4  = slen * 16;
        const float4* hn4 = (const float4*)(h_g + (size_t)n * (LL * DD));
        const int base = w * RPW * 16;              // first f4 of wave's span
        const int jmax = (nrows + 3) >> 2;          // 1..13 stage/PV groups

        // ---- stage: groups of 4 slots-of-64 (prefetch depth 4, 16 VGPR);
        //      each instr reads a contiguous 1KB; cvt_pk bf16, XOR swizzle ----
        for (int j0 = 0; j0 < jmax; j0 += 4) {
            float4 rn[4];
            #pragma unroll
            for (int u = 0; u < 4; ++u) {
                int i = (j0 + u) * 64 + lane;
                rn[u] = hn4[min(base + i, nf4 - 1)];   // clamp: L2 dup, finite
            }
            #pragma unroll
            for (int u = 0; u < 4; ++u) {
                int j = j0 + u;
                if (j < jmax) {
                    int i = j * 64 + lane;
                    int r = i >> 4, c = i & 15;        // r <= 51
                    hbw[r * 16 + (c ^ (r & 15))] =
                        make_uint2(pk2(rn[u].x, rn[u].y), pk2(rn[u].z, rn[u].w));
                }
            }
        }

        // hard per-head score bound (tanh in [-1,1]): same shift everywhere
        float Bk[KK];
        #pragma unroll
        for (int k = 0; k < KK; ++k) {
            float b = fabsf(W2b[k]);
            #pragma unroll
            for (int a = 0; a < AA; ++a) b += fabsf(W2w[k * AA + a]);
            Bk[k] = b;
        }

        asm volatile("s_waitcnt lgkmcnt(0)" ::: "memory");

        // ---- scores: lane = local row (dup-clamped to valid -> finite,
        //      broadcast reads free); W1 lane-uniform -> scalar loads.
        //      v2f accumulators -> v_pk_fma_f32 (2 FLOP-pairs/instr). ----
        const float4* W14 = (const float4*)W1w;
        const int rl = min(lane, nrows - 1);
        v2f A0 = {W1b[0], 0.f}, A1 = {W1b[1], 0.f}, A2 = {W1b[2], 0.f},
            A3 = {W1b[3], 0.f}, A4 = {W1b[4], 0.f};
        #pragma unroll
        for (int i = 0; i < 16; ++i) {
            uint2 q = hbw[rl * 16 + (i ^ (rl & 15))];
            v2f h01 = {lo16(q.x), hi16(q.x)};
            v2f h23 = {lo16(q.y), hi16(q.y)};
            float4 w0 = W14[0*16+i], w1 = W14[1*16+i], w2 = W14[2*16+i],
                   w3 = W14[3*16+i], w4 = W14[4*16+i];
            v2f w0a = {w0.x, w0.y}, w0b = {w0.z, w0.w};
            v2f w1a = {w1.x, w1.y}, w1b = {w1.z, w1.w};
            v2f w2a = {w2.x, w2.y}, w2b = {w2.z, w2.w};
            v2f w3a = {w3.x, w3.y}, w3b = {w3.z, w3.w};
            v2f w4a = {w4.x, w4.y}, w4b = {w4.z, w4.w};
            A0 = fma2(h01, w0a, A0); A0 = fma2(h23, w0b, A0);
            A1 = fma2(h01, w1a, A1); A1 = fma2(h23, w1b, A1);
            A2 = fma2(h01, w2a, A2); A2 = fma2(h23, w2b, A2);
            A3 = fma2(h01, w3a, A3); A3 = fma2(h23, w3b, A3);
            A4 = fma2(h01, w4a, A4); A4 = fma2(h23, w4b, A4);
        }
        const float a0 = A0.x + A0.y, a1 = A1.x + A1.y, a2 = A2.x + A2.y,
                    a3 = A3.x + A3.y, a4 = A4.x + A4.y;
        const bool vrow = lane < nrows;
        const float t0 = fast_tanh(a0), t1 = fast_tanh(a1), t2 = fast_tanh(a2),
                    t3 = fast_tanh(a3), t4 = fast_tanh(a4);
        float e[KK];
        #pragma unroll
        for (int k = 0; k < KK; ++k) {
            float s = W2b[k];
            s = fmaf(t0, W2w[k*AA+0], s);
            s = fmaf(t1, W2w[k*AA+1], s);
            s = fmaf(t2, W2w[k*AA+2], s);
            s = fmaf(t3, W2w[k*AA+3], s);
            s = fmaf(t4, W2w[k*AA+4], s);
            e[k] = vrow ? __expf(s - Bk[k]) : 0.f;         // e in (0,1]
        }
        if (lane < 52)
            p4s[w][lane] = make_float4(e[0], e[1], e[2], e[3]); // pads: e=0

        asm volatile("s_waitcnt lgkmcnt(0)" ::: "memory");

        // ---- PV: lane = (rq = lane>>4 row-in-group, dc = lane&15 slot);
        //      v2f accumulators -> v_pk_fma_f32. ----
        const int rq = lane >> 4, dc = lane & 15;
        v2f c0a = {0,0}, c0b = {0,0}, c1a = {0,0}, c1b = {0,0},
            c2a = {0,0}, c2b = {0,0}, c3a = {0,0}, c3b = {0,0};
        v2f dn01 = {0,0}, dn23 = {0,0};
        for (int g = 0; g < jmax; ++g) {
            const int row = g * 4 + rq;                    // <= 51; pads e=0
            uint2 q = hbw[row * 16 + (dc ^ (row & 15))];
            v2f h01 = {lo16(q.x), hi16(q.x)};
            v2f h23 = {lo16(q.y), hi16(q.y)};
            float4 pv = p4s[w][row];
            v2f p0 = {pv.x, pv.x}, p1 = {pv.y, pv.y},
                p2 = {pv.z, pv.z}, p3 = {pv.w, pv.w};
            c0a = fma2(p0, h01, c0a); c0b = fma2(p0, h23, c0b);
            c1a = fma2(p1, h01, c1a); c1b = fma2(p1, h23, c1b);
            c2a = fma2(p2, h01, c2a); c2b = fma2(p2, h23, c2b);
            c3a = fma2(p3, h01, c3a); c3b = fma2(p3, h23, c3b);
            v2f pv01 = {pv.x, pv.y}, pv23 = {pv.z, pv.w};
            dn01 += pv01; dn23 += pv23;                    // v_pk_add_f32
        }

        // ---- merge: rq-partials into OWN dead h region (no shuffles) ----
        *(float4*)&fregion[rq * 256 + 0 * 64 + dc * 4] =
            make_float4(c0a.x, c0a.y, c0b.x, c0b.y);
        *(float4*)&fregion[rq * 256 + 1 * 64 + dc * 4] =
            make_float4(c1a.x, c1a.y, c1b.x, c1b.y);
        *(float4*)&fregion[rq * 256 + 2 * 64 + dc * 4] =
            make_float4(c2a.x, c2a.y, c2b.x, c2b.y);
        *(float4*)&fregion[rq * 256 + 3 * 64 + dc * 4] =
            make_float4(c3a.x, c3a.y, c3b.x, c3b.y);
        if (dc == 0)
            *(float4*)&den_s[w][rq][0] =
                make_float4(dn01.x, dn01.y, dn23.x, dn23.y);
    }

    __syncthreads();

    // ---- epilogue: sum only the nact ACTIVE wave regions (block-uniform
    //      guards; inactive regions are never read -> no zeroing needed) ----
    {
        const float* fb = (const float*)hbuf;
        const int k = t >> 6;
        float s = 0.f, den = 0.f;
        #pragma unroll
        for (int wv = 0; wv < 4; ++wv) {
            if (wv < nact) {                               // uniform branch
                #pragma unroll
                for (int q = 0; q < 4; ++q) {
                    s   += fb[wv * FREG + q * 256 + t];    // stride-1 in t
                    den += den_s[wv][q][k];                // broadcast reads
                }
            }
        }
        out[(size_t)n * (KK * DD) + t] = s / den;          // den>0 (slen>=1)
    }
}

extern "C" void kernel_launch(void* const* d_in, const int* in_sizes, int n_in,
                              void* d_out, int out_size, void* d_ws, size_t ws_size,
                              hipStream_t stream) {
    const float* h_g  = (const float*)d_in[0];
    const int*   slen = (const int*)  d_in[1];
    const float* W1w  = (const float*)d_in[2];
    const float* W1b  = (const float*)d_in[3];
    const float* W2w  = (const float*)d_in[4];
    const float* W2b  = (const float*)d_in[5];
    float*       outp = (float*)d_out;

    const int N = in_sizes[1];

    mie_fused<<<dim3(N), dim3(256), 0, stream>>>(h_g, slen, W1w, W1b, W2w, W2b, outp);
}